// Round 9
// baseline (415.891 us; speedup 1.0000x reference)
//
#include <hip/hip_runtime.h>

#define N_NODES 20000
#define DIM 256
#define NHEAD 4
#define DHEAD 64
#define NLAYER 2
#define NEDGE 320000
#define KCAP 48
#define NBM64 313    // ceil(20000/64)
#define NBM32 625    // 20000/32 exactly

typedef __bf16 v8bf __attribute__((ext_vector_type(8)));
typedef __bf16 v2bf __attribute__((ext_vector_type(2)));
typedef float v4f __attribute__((ext_vector_type(4)));

union U32 { unsigned u; v2bf v; };

__device__ __forceinline__ unsigned short f2bf(float f) {
    unsigned u = __float_as_uint(f);
    unsigned r = u + 0x7FFFu + ((u >> 16) & 1u);   // RNE
    return (unsigned short)(r >> 16);
}
__device__ __forceinline__ float bflo(unsigned u) { return __uint_as_float(u << 16); }
__device__ __forceinline__ float bfhi(unsigned u) { return __uint_as_float(u & 0xFFFF0000u); }

// ---- async global->LDS (16B per lane; LDS dest = wave-uniform base) ---------
__device__ __forceinline__ void gl2lds(const void* g, void* l) {
    __builtin_amdgcn_global_load_lds(
        (const __attribute__((address_space(1))) unsigned int*)g,
        (__attribute__((address_space(3))) unsigned int*)l, 16, 0, 0);
}

// Stage one 8-row x 64-col bf16 group (1KB) into linear LDS with chunk-XOR
// pre-swizzle on the GLOBAL side (rule #21: swizzle both sides or neither).
__device__ __forceinline__ void stage8(const unsigned short* __restrict__ g0,
                                       size_t stride_e, unsigned short* lds) {
    const int l = threadIdx.x & 63;
    const int r = l >> 3;
    const int c = (l & 7) ^ r;
    gl2lds(g0 + (size_t)r * stride_e + c * 8, lds);
}
// A-side variant with row clamp.
__device__ __forceinline__ void stage8c(const unsigned short* __restrict__ base,
                                        int row0, int rowmax, size_t stride_e,
                                        int k0, unsigned short* lds) {
    const int l = threadIdx.x & 63;
    const int r = l >> 3;
    const int c = (l & 7) ^ r;
    int row = row0 + r; row = row > rowmax ? rowmax : row;
    gl2lds(base + (size_t)row * stride_e + k0 + c * 8, lds);
}

// Swizzled fragment read from a linear [rows][64] bf16 LDS tile (128B rows).
__device__ __forceinline__ v8bf frag_read(const unsigned short* lds, int row, int col2) {
    const int bo = row * 128 + (col2 ^ ((row & 7) << 4));
    return *(const v8bf*)((const char*)lds + bo);
}

// ---- BK=32 staging (r4-proven): 16 rows x 32 cols (64B/row, 1KB) per wave ---
// LDS[r][chunk s] = G[r][s ^ ((r>>1)&3)]; reads XOR the same bits.
__device__ __forceinline__ void stage16(const unsigned short* __restrict__ g0,
                                        size_t stride_e, unsigned short* lds) {
    const int l = threadIdx.x & 63;
    const int r = l >> 2;                       // 0..15
    const int c = (l & 3) ^ ((r >> 1) & 3);
    gl2lds(g0 + (size_t)r * stride_e + c * 8, lds);
}
__device__ __forceinline__ void stage16c(const unsigned short* __restrict__ base,
                                         int row0, int rowmax, size_t stride_e,
                                         int k0, unsigned short* lds) {
    const int l = threadIdx.x & 63;
    const int r = l >> 2;
    const int c = (l & 3) ^ ((r >> 1) & 3);
    int row = row0 + r; row = row > rowmax ? rowmax : row;
    gl2lds(base + (size_t)row * stride_e + k0 + c * 8, lds);
}

// Swizzled 16B fragment read from a [rows][32] bf16 tile (64B rows). t=0..3.
__device__ __forceinline__ v8bf frag32(const unsigned short* lds, int row, int t) {
    const int bo = row * 64 + (((t ^ ((row >> 1) & 3))) << 4);
    return *(const v8bf*)((const char*)lds + bo);
}

// =============== sniffer + cnt zero fused ====================================
__global__ void sniffzero_kernel(const unsigned short* __restrict__ p,
                                 int* __restrict__ flag, int* __restrict__ cnt) {
    if (blockIdx.x == 0) {
        __shared__ int s;
        if (threadIdx.x == 0) s = 0;
        __syncthreads();
        int c = 0;
        for (int i = threadIdx.x; i < 4096; i += 256) {
            unsigned short u = p[i];
            unsigned e = (u >> 7) & 0xFFu;
            if (e == 0xFFu) c++;
            else if (e == 0u && (u & 0x7Fu)) c++;
        }
        atomicAdd(&s, c);
        __syncthreads();
        if (threadIdx.x == 0) flag[0] = (s >= 4) ? 1 : 0;
    } else {
        int i = (blockIdx.x - 1) * 256 + threadIdx.x;
        if (i < N_NODES) cnt[i] = 0;
    }
}

// ===== conv to bf16 canon: 6 tensors (embeds + weights) ======================
struct ConvBfArgs { const void* src[6]; unsigned short* dst[6]; int n[6]; };

__global__ void conv_bf16_kernel(ConvBfArgs a, const int* __restrict__ flag) {
    const int t  = blockIdx.y;
    const int n  = a.n[t];
    const int i0 = (blockIdx.x * 256 + threadIdx.x) * 4;
    if (i0 >= n) return;
    unsigned short* dst = a.dst[t];
    if (flag[0]) {
        float4 v = *(const float4*)((const float*)a.src[t] + i0);
        ushort4 o;
        o.x = f2bf(v.x); o.y = f2bf(v.y); o.z = f2bf(v.z); o.w = f2bf(v.w);
        *(ushort4*)(dst + i0) = o;
    } else {
        ushort4 u = *(const ushort4*)((const unsigned short*)a.src[t] + i0);
        *(ushort4*)(dst + i0) = u;
    }
}

// ===== conv to fp32 canon: biases + LN params (8 small tensors) ==============
struct ConvF32Args { const void* src[8]; float* dst[8]; int n[8]; };

__global__ void conv_f32_kernel(ConvF32Args a, const int* __restrict__ flag) {
    const int t  = blockIdx.y;
    const int n  = a.n[t];
    const int i0 = (blockIdx.x * 256 + threadIdx.x) * 4;
    if (i0 >= n) return;
    float* dst = a.dst[t];
    if (flag[0]) {
        float4 v = *(const float4*)((const float*)a.src[t] + i0);
        *(float4*)(dst + i0) = v;
    } else {
        ushort4 u = *(const ushort4*)((const unsigned short*)a.src[t] + i0);
        *(float4*)(dst + i0) = make_float4(bflo(u.x), bflo(u.y), bflo(u.z), bflo(u.w));
    }
}

__global__ void build_nbr_kernel(const int* __restrict__ ei,
                                 int* __restrict__ cnt, int* __restrict__ nbr) {
    int e = blockIdx.x * 256 + threadIdx.x;
    if (e >= NEDGE) return;
    int s = ei[e];
    int t = ei[NEDGE + e];
    int slot = atomicAdd(&cnt[t], 1);
    if (slot < KCAP) nbr[t * KCAP + slot] = s;
}

// ==== MFMA GEMM body: 64x128 tile, BK=64, glds staging (r5-best structure) ===
__device__ __forceinline__ void gemm_body64(
    unsigned short* At, unsigned short* Bt,
    const unsigned short* __restrict__ A, const unsigned short* __restrict__ B,
    const float* __restrict__ bias, unsigned short* __restrict__ C,
    int M, int Nc, int Kd, int m0, int nB, int nC, int do_gelu)
{
    const int tid  = threadIdx.x;
    const int wave = tid >> 6;
    const int lane = tid & 63;
    const int wr   = (wave >> 1) * 32;
    const int wc   = (wave & 1) * 64;
    const int lm   = lane & 15;
    const int lk   = (lane >> 4) * 8;

    v4f acc[2][4] = {};

    for (int k0 = 0; k0 < Kd; k0 += 64) {
#pragma unroll
        for (int i = 0; i < 2; ++i) {
            const int rr = wave * 16 + i * 8;
            stage8c(A, m0 + rr, M - 1, Kd, k0, At + rr * 64);
        }
#pragma unroll
        for (int i = 0; i < 4; ++i) {
            const int rr = wave * 32 + i * 8;
            stage8(B + (size_t)(nB + rr) * Kd + k0, Kd, Bt + rr * 64);
        }
        __syncthreads();

#pragma unroll
        for (int ks = 0; ks < 2; ++ks) {
            v8bf af[2], bq[4];
#pragma unroll
            for (int mi = 0; mi < 2; ++mi)
                af[mi] = frag_read(At, wr + mi * 16 + lm, (ks * 32 + lk) * 2);
#pragma unroll
            for (int ni = 0; ni < 4; ++ni)
                bq[ni] = frag_read(Bt, wc + ni * 16 + lm, (ks * 32 + lk) * 2);
#pragma unroll
            for (int mi = 0; mi < 2; ++mi)
#pragma unroll
                for (int ni = 0; ni < 4; ++ni)
                    acc[mi][ni] = __builtin_amdgcn_mfma_f32_16x16x32_bf16(
                        af[mi], bq[ni], acc[mi][ni], 0, 0, 0);
        }
        __syncthreads();
    }

    const int rq = (lane >> 4) << 2;
#pragma unroll
    for (int ni = 0; ni < 4; ++ni) {
        int colb = wc + ni * 16 + lm;
        float bv = bias[nB + colb];
        int colc = nC + colb;
#pragma unroll
        for (int mi = 0; mi < 2; ++mi) {
#pragma unroll
            for (int r = 0; r < 4; ++r) {
                int row = m0 + wr + mi * 16 + rq + r;
                if (row >= M) continue;
                float v = acc[mi][ni][r] + bv;
                if (do_gelu) v = 0.5f * v * (1.0f + erff(v * 0.7071067811865475f));
                C[(size_t)row * Nc + colc] = f2bf(v);
            }
        }
    }
}

// Generic GEMM (used for ffn1): grid (ceil(M/64), Nc/128)
__global__ __launch_bounds__(256) void gemm_kernel(
    const unsigned short* __restrict__ A, const unsigned short* __restrict__ B,
    const float* __restrict__ bias, unsigned short* __restrict__ C,
    int M, int Nc, int Kd, int do_gelu)
{
    __shared__ __align__(1024) unsigned short At[64 * 64];
    __shared__ __align__(1024) unsigned short Bt[128 * 64];
    const int n0 = blockIdx.y * 128;
    gemm_body64(At, Bt, A, B, bias, C, M, Nc, Kd, blockIdx.x * 64, n0, n0, do_gelu);
}

// Fused q+kv projection: grid (ceil(M/64), 6)
__global__ __launch_bounds__(256) void qkv_kernel(
    const unsigned short* __restrict__ x, const unsigned short* __restrict__ spat,
    const unsigned short* __restrict__ W, const float* __restrict__ bias,
    unsigned short* __restrict__ q, unsigned short* __restrict__ kv, int M)
{
    __shared__ __align__(1024) unsigned short At[64 * 64];
    __shared__ __align__(1024) unsigned short Bt[128 * 64];
    const int y = blockIdx.y;
    const unsigned short* A = (y < 2) ? x : spat;
    unsigned short*       C = (y < 2) ? q : kv;
    const int Nc = (y < 2) ? 256 : 512;
    const int nB = y * 128;
    const int nC = (y < 2) ? nB : nB - 256;
    gemm_body64(At, Bt, A, W, bias, C, M, Nc, 256, blockIdx.x * 64, nB, nC, 0);
}

// ==== Fused GEMM + residual + LayerNorm: tile 32 x 256, BK=32 ================
// r19: BK=32 shrinks LDS 38KB -> ~20KB => LDS cap 8 blocks/CU (was 4);
// launch_bounds(256,6) keeps VGPR <= ~85 so >=6 blocks/CU are schedulable.
// More K-steps (8 vs 4), but r5 proved block-level TLP is what hides the
// staging latency in these short-K GEMMs.
__global__ __launch_bounds__(256, 6) void gemm_ln_kernel(
    const unsigned short* __restrict__ A, const unsigned short* __restrict__ B,
    const float* __restrict__ bias, const unsigned short* __restrict__ xres,
    const float* __restrict__ g, const float* __restrict__ bb,
    unsigned short* __restrict__ xout, void* __restrict__ dout,
    int M, int Kd, int final_out, const int* __restrict__ flag)
{
    __shared__ __align__(1024) unsigned short At[32 * 32];
    __shared__ __align__(1024) unsigned short Bt[256 * 32];
    __shared__ float partS[4][32], partSS[4][32];
    __shared__ float totMu[32], totR[32];

    const int tid  = threadIdx.x;
    const int m0   = blockIdx.x * 32;
    const int wave = tid >> 6;
    const int lane = tid & 63;
    const int wn0  = wave * 64;
    const int lm   = lane & 15;
    const int lt   = lane >> 4;          // k-chunk 0..3

    v4f acc[2][4] = {};

    for (int k0 = 0; k0 < Kd; k0 += 32) {
        // A tile 32x32: waves 0-1 stage 16 rows each; B tile 256x32: all waves
        if (wave < 2)
            stage16c(A, m0 + wave * 16, M - 1, Kd, k0, At + wave * 16 * 32);
#pragma unroll
        for (int i = 0; i < 4; ++i) {
            const int rr = wave * 64 + i * 16;
            stage16(B + (size_t)rr * Kd + k0, Kd, Bt + rr * 32);
        }
        __syncthreads();

        v8bf af[2], bq[4];
#pragma unroll
        for (int mi = 0; mi < 2; ++mi)
            af[mi] = frag32(At, mi * 16 + lm, lt);
#pragma unroll
        for (int ni = 0; ni < 4; ++ni)
            bq[ni] = frag32(Bt, wn0 + ni * 16 + lm, lt);
#pragma unroll
        for (int mi = 0; mi < 2; ++mi)
#pragma unroll
            for (int ni = 0; ni < 4; ++ni)
                acc[mi][ni] = __builtin_amdgcn_mfma_f32_16x16x32_bf16(
                    af[mi], bq[ni], acc[mi][ni], 0, 0, 0);
        __syncthreads();
    }

    const int rq = (lane >> 4) << 2;
    float gv[4], bv2[4], biasv[4];
#pragma unroll
    for (int ni = 0; ni < 4; ++ni) {
        int col = wn0 + ni * 16 + lm;
        biasv[ni] = bias[col];
        gv[ni]    = g[col];
        bv2[ni]   = bb[col];
    }

    float sl[2][4] = {}, ssl[2][4] = {};
#pragma unroll
    for (int mi = 0; mi < 2; ++mi) {
#pragma unroll
        for (int r = 0; r < 4; ++r) {
            int row = m0 + mi * 16 + rq + r;
#pragma unroll
            for (int ni = 0; ni < 4; ++ni) {
                int col = wn0 + ni * 16 + lm;
                float resv = bflo((unsigned)xres[(size_t)row * DIM + col]);
                float v = acc[mi][ni][r] + biasv[ni] + resv;
                acc[mi][ni][r] = v;
                sl[mi][r]  += v;
                ssl[mi][r] += v * v;
            }
        }
    }
#pragma unroll
    for (int mi = 0; mi < 2; ++mi)
#pragma unroll
        for (int r = 0; r < 4; ++r) {
#pragma unroll
            for (int m = 1; m <= 8; m <<= 1) {
                sl[mi][r]  += __shfl_xor(sl[mi][r],  m, 64);
                ssl[mi][r] += __shfl_xor(ssl[mi][r], m, 64);
            }
        }
    if (lm == 0) {
#pragma unroll
        for (int mi = 0; mi < 2; ++mi)
#pragma unroll
            for (int r = 0; r < 4; ++r) {
                partS[wave][mi * 16 + rq + r]  = sl[mi][r];
                partSS[wave][mi * 16 + rq + r] = ssl[mi][r];
            }
    }
    __syncthreads();
    if (tid < 32) {
        float S = partS[0][tid] + partS[1][tid] + partS[2][tid] + partS[3][tid];
        float SS = partSS[0][tid] + partSS[1][tid] + partSS[2][tid] + partSS[3][tid];
        float mu  = S * (1.0f / DIM);
        float var = SS * (1.0f / DIM) - mu * mu;
        totMu[tid] = mu;
        totR[tid]  = rsqrtf(var + 1e-5f);
    }
    __syncthreads();

#pragma unroll
    for (int mi = 0; mi < 2; ++mi) {
#pragma unroll
        for (int r = 0; r < 4; ++r) {
            int lrow = mi * 16 + rq + r;
            int row  = m0 + lrow;
            float mu = totMu[lrow];
            float rv = totR[lrow];
#pragma unroll
            for (int ni = 0; ni < 4; ++ni) {
                int col = wn0 + ni * 16 + lm;
                float o = (acc[mi][ni][r] - mu) * rv * gv[ni] + bv2[ni];
                if (final_out) {
                    if (flag[0]) ((float*)dout)[(size_t)row * DIM + col] = o;
                    else ((unsigned short*)dout)[(size_t)row * DIM + col] = f2bf(o);
                } else {
                    xout[(size_t)row * DIM + col] = f2bf(o);
                }
            }
        }
    }
}

// ====== attention: block per node, wave per head; barrier-free ===============
// r19: reverted to r5's guarded prefetch (proven 48.7us). r18's branch-free
// version regressed (+8us): 2.5x extra score-phase VALU work for no pipeline
// gain. attn is within ~8% of its gather-BW floor (138.7MB @ ~3.1TB/s).
__global__ __launch_bounds__(256) void attn_kernel(
    const unsigned short* __restrict__ q,    // [N, 256]
    const unsigned short* __restrict__ kv,   // [N, 512] (k | v)
    const int* __restrict__ nbr,             // [N, KCAP]
    const int* __restrict__ cnt,             // [N]
    unsigned short* __restrict__ ao)         // [N, 256]
{
    const int n    = blockIdx.x;
    const int tid  = threadIdx.x;
    const int h    = tid >> 6;
    const int lane = tid & 63;

    __shared__ float sc[NHEAD][KCAP];
    __shared__ int   nbs[NHEAD][KCAP];

    int deg = cnt[n];
    if (deg > KCAP) deg = KCAP;
    const bool iso = (deg == 0);
    if (iso) deg = 1;

    // per-wave neighbor list (no cross-wave sharing -> no barriers anywhere)
    if (lane < KCAP)
        nbs[h][lane] = (lane < deg) ? (iso ? n : nbr[n * KCAP + lane]) : 0;

    // ---- score-phase geometry: 8 lane-groups of 8 ----
    const int sub = lane & 7;
    const int grp = lane >> 3;
    const uint4 qu = *(const uint4*)&q[(size_t)n * DIM + h * DHEAD + sub * 8];
    const unsigned short* kbase = kv + h * DHEAD + sub * 8;
    const int nit = (deg + 7) >> 3;          // 1..6

    // ---- PV geometry: 4 lane-quarters of 16 ----
    const int quarter = lane >> 4;
    const int d0      = (lane & 15) * 4;
    const unsigned short* vbase = kv + 256 + h * DHEAD + d0;
    const int dmax = (deg + 3) & ~3;
    const int npv  = dmax >> 2;              // 1..12

    // ---- prefetch: issue ALL k loads, then all v loads (deg<=32 fast path) --
    uint4 ku[6];
#pragma unroll
    for (int it = 0; it < 6; ++it) {
        if (it < nit) {
            int nb = nbs[h][it * 8 + grp];
            ku[it] = *(const uint4*)&kbase[(size_t)nb * 512];
        }
    }
    uint2 vu[8];
#pragma unroll
    for (int it = 0; it < 8; ++it) {
        if (it < npv) {
            int nb = nbs[h][it * 4 + quarter];
            vu[it] = *(const uint2*)&vbase[(size_t)nb * 512];
        }
    }

    // ---- scores (consume ku; v loads stay in flight) ----
#pragma unroll
    for (int it = 0; it < 6; ++it) {
        if (it < nit) {
            int j = it * 8 + grp;
            uint4 kz = ku[it];
#if __has_builtin(__builtin_amdgcn_fdot2_f32_bf16)
            U32 a0{qu.x}, a1{qu.y}, a2{qu.z}, a3{qu.w};
            U32 b0{kz.x}, b1{kz.y}, b2{kz.z}, b3{kz.w};
            float p = __builtin_amdgcn_fdot2_f32_bf16(a0.v, b0.v, 0.0f, false);
            p = __builtin_amdgcn_fdot2_f32_bf16(a1.v, b1.v, p, false);
            p = __builtin_amdgcn_fdot2_f32_bf16(a2.v, b2.v, p, false);
            p = __builtin_amdgcn_fdot2_f32_bf16(a3.v, b3.v, p, false);
#else
            float p = bflo(qu.x) * bflo(kz.x);
            p = fmaf(bfhi(qu.x), bfhi(kz.x), p);
            p = fmaf(bflo(qu.y), bflo(kz.y), p);
            p = fmaf(bfhi(qu.y), bfhi(kz.y), p);
            p = fmaf(bflo(qu.z), bflo(kz.z), p);
            p = fmaf(bfhi(qu.z), bfhi(kz.z), p);
            p = fmaf(bflo(qu.w), bflo(kz.w), p);
            p = fmaf(bfhi(qu.w), bfhi(kz.w), p);
#endif
            p += __shfl_xor(p, 1, 64);
            p += __shfl_xor(p, 2, 64);
            p += __shfl_xor(p, 4, 64);
            if (sub == 0 && j < deg) sc[h][j] = p * 0.125f;   // 1/sqrt(64)
        }
    }

    // ---- softmax (per wave; sc is wave-private; v-gather hides under it) ----
    {
        float s  = (lane < deg) ? sc[h][lane] : -1e30f;
        float mx = s;
#pragma unroll
        for (int m = 32; m >= 1; m >>= 1) mx = fmaxf(mx, __shfl_xor(mx, m, 64));
        float e   = (lane < deg) ? __expf(s - mx) : 0.0f;
        float sum = e;
#pragma unroll
        for (int m = 32; m >= 1; m >>= 1) sum += __shfl_xor(sum, m, 64);
        float inv = 1.0f / sum;
        if (lane < KCAP) sc[h][lane] = e * inv;   // zero for lane >= deg
    }

    // ---- PV: consume prefetched v; dynamic remainder for deg > 32 ----
    {
        float a0 = 0.f, a1 = 0.f, a2 = 0.f, a3 = 0.f;
#pragma unroll
        for (int it = 0; it < 8; ++it) {
            if (it < npv) {
                float w = sc[h][it * 4 + quarter];
                uint2 u = vu[it];
                a0 = fmaf(w, bflo(u.x), a0);
                a1 = fmaf(w, bfhi(u.x), a1);
                a2 = fmaf(w, bflo(u.y), a2);
                a3 = fmaf(w, bfhi(u.y), a3);
            }
        }
        for (int j = 32; j < dmax; j += 4) {      // rare: deg in (32, 48]
            int j0 = j + quarter;
            int nb = nbs[h][j0];
            uint2 u = *(const uint2*)&vbase[(size_t)nb * 512];
            float w = sc[h][j0];
            a0 = fmaf(w, bflo(u.x), a0);
            a1 = fmaf(w, bfhi(u.x), a1);
            a2 = fmaf(w, bflo(u.y), a2);
            a3 = fmaf(w, bfhi(u.y), a3);
        }
        a0 += __shfl_xor(a0, 16, 64); a0 += __shfl_xor(a0, 32, 64);
        a1 += __shfl_xor(a1, 16, 64); a1 += __shfl_xor(a1, 32, 64);
        a2 += __shfl_xor(a2, 16, 64); a2 += __shfl_xor(a2, 32, 64);
        a3 += __shfl_xor(a3, 16, 64); a3 += __shfl_xor(a3, 32, 64);
        if (lane < 16) {
            uint2 o;
            o.x = (unsigned)f2bf(a0) | ((unsigned)f2bf(a1) << 16);
            o.y = (unsigned)f2bf(a2) | ((unsigned)f2bf(a3) << 16);
            *(uint2*)&ao[(size_t)n * DIM + h * DHEAD + d0] = o;
        }
    }
}

// =============== launch ======================================================
extern "C" void kernel_launch(void* const* d_in, const int* in_sizes, int n_in,
                              void* d_out, int out_size, void* d_ws, size_t ws_size,
                              hipStream_t stream) {
    const int* ei = (const int*)d_in[14];

    char* ws = (char*)d_ws;
    size_t off = 0;
    auto alloc = [&](size_t bytes) -> void* {
        void* p = ws + off;
        off = (off + bytes + 255) & ~(size_t)255;
        return p;
    };

    const int bidx[6] = { 0, 1, 2, 4, 6, 8 };
    const int bnn[6]  = { N_NODES * DIM, N_NODES * DIM,
                          NLAYER * 3 * DIM * DIM, NLAYER * DIM * DIM,
                          NLAYER * 2 * DIM * DIM, NLAYER * DIM * 2 * DIM };
    ConvBfArgs cb;
    unsigned short* canb[6];
    for (int i = 0; i < 6; ++i) {
        canb[i] = (unsigned short*)alloc((size_t)bnn[i] * 2);
        cb.src[i] = d_in[bidx[i]];
        cb.dst[i] = canb[i];
        cb.n[i]   = bnn[i];
    }
    const unsigned short* expr_b = canb[0];
    const unsigned short* spat_b = canb[1];
    const unsigned short* ipw    = canb[2];
    const unsigned short* opw    = canb[3];
    const unsigned short* w1     = canb[4];
    const unsigned short* w2     = canb[5];

    const int fidx[8] = { 3, 5, 7, 9, 10, 11, 12, 13 };
    const int fn[8]   = { NLAYER * 3 * DIM, NLAYER * DIM, NLAYER * 2 * DIM,
                          NLAYER * DIM, NLAYER * DIM, NLAYER * DIM,
                          NLAYER * DIM, NLAYER * DIM };
    ConvF32Args cf;
    float* canf[8];
    for (int i = 0; i < 8; ++i) {
        canf[i] = (float*)alloc((size_t)fn[i] * 4);
        cf.src[i] = d_in[fidx[i]];
        cf.dst[i] = canf[i];
        cf.n[i]   = fn[i];
    }

    unsigned short* x_buf  = (unsigned short*)alloc((size_t)N_NODES * DIM * 2);
    unsigned short* q_buf  = (unsigned short*)alloc((size_t)N_NODES * DIM * 2);
    unsigned short* kv_buf = (unsigned short*)alloc((size_t)N_NODES * 2 * DIM * 2);
    unsigned short* ao_buf = (unsigned short*)alloc((size_t)N_NODES * DIM * 2);
    unsigned short* h_buf  = (unsigned short*)alloc((size_t)N_NODES * 2 * DIM * 2);
    int* cnt  = (int*)alloc((size_t)N_NODES * 4);
    int* nbr  = (int*)alloc((size_t)N_NODES * KCAP * 4);
    int* flag = (int*)alloc(256);

    sniffzero_kernel<<<1 + (N_NODES + 255) / 256, 256, 0, stream>>>(
        (const unsigned short*)d_in[0], flag, cnt);
    conv_bf16_kernel<<<dim3((N_NODES * DIM) / 1024, 6), 256, 0, stream>>>(cb, flag);
    conv_f32_kernel<<<dim3(2, 8), 256, 0, stream>>>(cf, flag);
    build_nbr_kernel<<<(NEDGE + 255) / 256, 256, 0, stream>>>(ei, cnt, nbr);

    for (int i = 0; i < NLAYER; ++i) {
        const unsigned short* Wqkv = ipw + (size_t)i * 3 * DIM * DIM;
        const float*          bqkv = canf[0] + (size_t)i * 3 * DIM;
        const unsigned short* xin  = (i == 0) ? expr_b : x_buf;

        // q | kv fused projection (64x128 tiles, high TLP)
        qkv_kernel<<<dim3(NBM64, 6), 256, 0, stream>>>(
            xin, spat_b, Wqkv, bqkv, q_buf, kv_buf, N_NODES);
        // attention (r5-proven guarded prefetch)
        attn_kernel<<<N_NODES, 256, 0, stream>>>(q_buf, kv_buf, nbr, cnt, ao_buf);
        // x = LN(xin + ao @ Wo^T + bo)  (BM=32, BK=32, grid 625)
        gemm_ln_kernel<<<NBM32, 256, 0, stream>>>(
            ao_buf, opw + (size_t)i * DIM * DIM, canf[1] + (size_t)i * DIM,
            xin, canf[4] + (size_t)i * DIM, canf[5] + (size_t)i * DIM,
            x_buf, nullptr, N_NODES, DIM, 0, flag);
        // h = gelu(x @ W1^T + b1)  (64x128 tiles)
        gemm_kernel<<<dim3(NBM64, 4), 256, 0, stream>>>(
            x_buf, w1 + (size_t)i * 2 * DIM * DIM, canf[2] + (size_t)i * 2 * DIM,
            h_buf, N_NODES, 2 * DIM, DIM, 1);
        // x = LN(x + h @ W2^T + b2); final layer -> d_out (dtype per flag)
        gemm_ln_kernel<<<NBM32, 256, 0, stream>>>(
            h_buf, w2 + (size_t)i * DIM * 2 * DIM, canf[3] + (size_t)i * DIM,
            x_buf, canf[6] + (size_t)i * DIM, canf[7] + (size_t)i * DIM,
            x_buf, d_out, N_NODES, 2 * DIM, (i == NLAYER - 1) ? 1 : 0, flag);
    }
}

// Round 10
// 398.281 us; speedup vs baseline: 1.0442x; 1.0442x over previous
//
#include <hip/hip_runtime.h>

#define N_NODES 20000
#define DIM 256
#define NHEAD 4
#define DHEAD 64
#define NLAYER 2
#define NEDGE 320000
#define KCAP 48
#define NBM64 313    // ceil(20000/64)
#define NBM32 625    // 20000/32 exactly

typedef __bf16 v8bf __attribute__((ext_vector_type(8)));
typedef __bf16 v2bf __attribute__((ext_vector_type(2)));
typedef float v4f __attribute__((ext_vector_type(4)));

union U32 { unsigned u; v2bf v; };

__device__ __forceinline__ unsigned short f2bf(float f) {
    unsigned u = __float_as_uint(f);
    unsigned r = u + 0x7FFFu + ((u >> 16) & 1u);   // RNE
    return (unsigned short)(r >> 16);
}
__device__ __forceinline__ float bflo(unsigned u) { return __uint_as_float(u << 16); }
__device__ __forceinline__ float bfhi(unsigned u) { return __uint_as_float(u & 0xFFFF0000u); }

// ---- async global->LDS (16B per lane; LDS dest = wave-uniform base) ---------
__device__ __forceinline__ void gl2lds(const void* g, void* l) {
    __builtin_amdgcn_global_load_lds(
        (const __attribute__((address_space(1))) unsigned int*)g,
        (__attribute__((address_space(3))) unsigned int*)l, 16, 0, 0);
}

// Stage one 8-row x 64-col bf16 group (1KB) into linear LDS with chunk-XOR
// pre-swizzle on the GLOBAL side (rule #21: swizzle both sides or neither).
__device__ __forceinline__ void stage8(const unsigned short* __restrict__ g0,
                                       size_t stride_e, unsigned short* lds) {
    const int l = threadIdx.x & 63;
    const int r = l >> 3;
    const int c = (l & 7) ^ r;
    gl2lds(g0 + (size_t)r * stride_e + c * 8, lds);
}
// A-side variant with row clamp (clamped rows give garbage acc rows that are
// never stored).
__device__ __forceinline__ void stage8c(const unsigned short* __restrict__ base,
                                        int row0, int rowmax, size_t stride_e,
                                        int k0, unsigned short* lds) {
    const int l = threadIdx.x & 63;
    const int r = l >> 3;
    const int c = (l & 7) ^ r;
    int row = row0 + r; row = row > rowmax ? rowmax : row;
    gl2lds(base + (size_t)row * stride_e + k0 + c * 8, lds);
}

// Swizzled fragment read from a linear [rows][64] bf16 LDS tile (128B rows).
// col2 = byte column (pre-swizzle), multiple of 16. 2-way bank alias = free.
__device__ __forceinline__ v8bf frag_read(const unsigned short* lds, int row, int col2) {
    const int bo = row * 128 + (col2 ^ ((row & 7) << 4));
    return *(const v8bf*)((const char*)lds + bo);
}

// =============== sniffer + cnt zero fused ====================================
__global__ void sniffzero_kernel(const unsigned short* __restrict__ p,
                                 int* __restrict__ flag, int* __restrict__ cnt) {
    if (blockIdx.x == 0) {
        __shared__ int s;
        if (threadIdx.x == 0) s = 0;
        __syncthreads();
        int c = 0;
        for (int i = threadIdx.x; i < 4096; i += 256) {
            unsigned short u = p[i];
            unsigned e = (u >> 7) & 0xFFu;
            if (e == 0xFFu) c++;
            else if (e == 0u && (u & 0x7Fu)) c++;
        }
        atomicAdd(&s, c);
        __syncthreads();
        if (threadIdx.x == 0) flag[0] = (s >= 4) ? 1 : 0;
    } else {
        int i = (blockIdx.x - 1) * 256 + threadIdx.x;
        if (i < N_NODES) cnt[i] = 0;
    }
}

// ===== r20: merged prep: bf16 conv (y<6) | f32 conv (y==6) | nbr (y==7) ======
// All three depend only on sniffzero (flag + zeroed cnt) and are mutually
// independent -> one dispatch instead of three; small work rides under the
// big conv instead of serializing after it (single stream = sum of dispatch
// times, so dispatch count is the lever).
struct ConvBfArgs { const void* src[6]; unsigned short* dst[6]; int n[6]; };
struct ConvF32Args { const void* src[8]; float* dst[8]; int n[8]; };

__global__ void prep_kernel(ConvBfArgs a, ConvF32Args cf,
                            const int* __restrict__ ei,
                            int* __restrict__ cnt, int* __restrict__ nbr,
                            const int* __restrict__ flag) {
    const int y = blockIdx.y;
    if (y < 6) {
        const int n  = a.n[y];
        const int i0 = (blockIdx.x * 256 + threadIdx.x) * 4;
        if (i0 >= n) return;
        unsigned short* dst = a.dst[y];
        if (flag[0]) {
            float4 v = *(const float4*)((const float*)a.src[y] + i0);
            ushort4 o;
            o.x = f2bf(v.x); o.y = f2bf(v.y); o.z = f2bf(v.z); o.w = f2bf(v.w);
            *(ushort4*)(dst + i0) = o;
        } else {
            ushort4 u = *(const ushort4*)((const unsigned short*)a.src[y] + i0);
            *(ushort4*)(dst + i0) = u;
        }
    } else if (y == 6) {
        if (blockIdx.x >= 2) return;
        const int i0 = (blockIdx.x * 256 + threadIdx.x) * 4;
        const int f = flag[0];
#pragma unroll
        for (int t = 0; t < 8; ++t) {
            const int n = cf.n[t];
            if (i0 >= n) continue;
            float* dst = cf.dst[t];
            if (f) {
                float4 v = *(const float4*)((const float*)cf.src[t] + i0);
                *(float4*)(dst + i0) = v;
            } else {
                ushort4 u = *(const ushort4*)((const unsigned short*)cf.src[t] + i0);
                *(float4*)(dst + i0) =
                    make_float4(bflo(u.x), bflo(u.y), bflo(u.z), bflo(u.w));
            }
        }
    } else {
        const int e = blockIdx.x * 256 + threadIdx.x;
        if (e >= NEDGE) return;
        int s = ei[e];
        int t = ei[NEDGE + e];
        int slot = atomicAdd(&cnt[t], 1);
        if (slot < KCAP) nbr[t * KCAP + slot] = s;
    }
}

// ==== MFMA GEMM body: 64x128 tile, BK=64, glds staging (r5-best structure) ===
__device__ __forceinline__ void gemm_body64(
    unsigned short* At, unsigned short* Bt,
    const unsigned short* __restrict__ A, const unsigned short* __restrict__ B,
    const float* __restrict__ bias, unsigned short* __restrict__ C,
    int M, int Nc, int Kd, int m0, int nB, int nC, int do_gelu)
{
    const int tid  = threadIdx.x;
    const int wave = tid >> 6;
    const int lane = tid & 63;
    const int wr   = (wave >> 1) * 32;
    const int wc   = (wave & 1) * 64;
    const int lm   = lane & 15;
    const int lk   = (lane >> 4) * 8;

    v4f acc[2][4] = {};

    for (int k0 = 0; k0 < Kd; k0 += 64) {
#pragma unroll
        for (int i = 0; i < 2; ++i) {
            const int rr = wave * 16 + i * 8;
            stage8c(A, m0 + rr, M - 1, Kd, k0, At + rr * 64);
        }
#pragma unroll
        for (int i = 0; i < 4; ++i) {
            const int rr = wave * 32 + i * 8;
            stage8(B + (size_t)(nB + rr) * Kd + k0, Kd, Bt + rr * 64);
        }
        __syncthreads();

#pragma unroll
        for (int ks = 0; ks < 2; ++ks) {
            v8bf af[2], bq[4];
#pragma unroll
            for (int mi = 0; mi < 2; ++mi)
                af[mi] = frag_read(At, wr + mi * 16 + lm, (ks * 32 + lk) * 2);
#pragma unroll
            for (int ni = 0; ni < 4; ++ni)
                bq[ni] = frag_read(Bt, wc + ni * 16 + lm, (ks * 32 + lk) * 2);
#pragma unroll
            for (int mi = 0; mi < 2; ++mi)
#pragma unroll
                for (int ni = 0; ni < 4; ++ni)
                    acc[mi][ni] = __builtin_amdgcn_mfma_f32_16x16x32_bf16(
                        af[mi], bq[ni], acc[mi][ni], 0, 0, 0);
        }
        __syncthreads();
    }

    const int rq = (lane >> 4) << 2;
#pragma unroll
    for (int ni = 0; ni < 4; ++ni) {
        int colb = wc + ni * 16 + lm;
        float bv = bias[nB + colb];
        int colc = nC + colb;
#pragma unroll
        for (int mi = 0; mi < 2; ++mi) {
#pragma unroll
            for (int r = 0; r < 4; ++r) {
                int row = m0 + wr + mi * 16 + rq + r;
                if (row >= M) continue;
                float v = acc[mi][ni][r] + bv;
                if (do_gelu) v = 0.5f * v * (1.0f + erff(v * 0.7071067811865475f));
                C[(size_t)row * Nc + colc] = f2bf(v);
            }
        }
    }
}

// Generic GEMM (used for ffn1): grid (ceil(M/64), Nc/128)
__global__ __launch_bounds__(256) void gemm_kernel(
    const unsigned short* __restrict__ A, const unsigned short* __restrict__ B,
    const float* __restrict__ bias, unsigned short* __restrict__ C,
    int M, int Nc, int Kd, int do_gelu)
{
    __shared__ __align__(1024) unsigned short At[64 * 64];
    __shared__ __align__(1024) unsigned short Bt[128 * 64];
    const int n0 = blockIdx.y * 128;
    gemm_body64(At, Bt, A, B, bias, C, M, Nc, Kd, blockIdx.x * 64, n0, n0, do_gelu);
}

// Fused q+kv projection: grid (ceil(M/64), 6)
__global__ __launch_bounds__(256) void qkv_kernel(
    const unsigned short* __restrict__ x, const unsigned short* __restrict__ spat,
    const unsigned short* __restrict__ W, const float* __restrict__ bias,
    unsigned short* __restrict__ q, unsigned short* __restrict__ kv, int M)
{
    __shared__ __align__(1024) unsigned short At[64 * 64];
    __shared__ __align__(1024) unsigned short Bt[128 * 64];
    const int y = blockIdx.y;
    const unsigned short* A = (y < 2) ? x : spat;
    unsigned short*       C = (y < 2) ? q : kv;
    const int Nc = (y < 2) ? 256 : 512;
    const int nB = y * 128;
    const int nC = (y < 2) ? nB : nB - 256;
    gemm_body64(At, Bt, A, W, bias, C, M, Nc, 256, blockIdx.x * 64, nB, nC, 0);
}

// ==== Fused GEMM + residual + LayerNorm: tile 32 x 256 (r5-proven, BK=64) ====
__global__ __launch_bounds__(256) void gemm_ln_kernel(
    const unsigned short* __restrict__ A, const unsigned short* __restrict__ B,
    const float* __restrict__ bias, const unsigned short* __restrict__ xres,
    const float* __restrict__ g, const float* __restrict__ bb,
    unsigned short* __restrict__ xout, void* __restrict__ dout,
    int M, int Kd, int final_out, const int* __restrict__ flag)
{
    __shared__ __align__(1024) unsigned short At[32 * 64];
    __shared__ __align__(1024) unsigned short Bt[256 * 64];
    __shared__ float partS[4][32], partSS[4][32];
    __shared__ float totMu[32], totR[32];

    const int tid  = threadIdx.x;
    const int m0   = blockIdx.x * 32;
    const int wave = tid >> 6;
    const int lane = tid & 63;
    const int wn0  = wave * 64;
    const int lm   = lane & 15;
    const int lk   = (lane >> 4) * 8;

    v4f acc[2][4] = {};

    for (int k0 = 0; k0 < Kd; k0 += 64) {
        {
            const int rr = wave * 8;
            stage8c(A, m0 + rr, M - 1, Kd, k0, At + rr * 64);
        }
#pragma unroll
        for (int i = 0; i < 8; ++i) {
            const int rr = wave * 64 + i * 8;
            stage8(B + (size_t)rr * Kd + k0, Kd, Bt + rr * 64);
        }
        __syncthreads();

#pragma unroll
        for (int ks = 0; ks < 2; ++ks) {
            v8bf af[2], bq[4];
#pragma unroll
            for (int mi = 0; mi < 2; ++mi)
                af[mi] = frag_read(At, mi * 16 + lm, (ks * 32 + lk) * 2);
#pragma unroll
            for (int ni = 0; ni < 4; ++ni)
                bq[ni] = frag_read(Bt, wn0 + ni * 16 + lm, (ks * 32 + lk) * 2);
#pragma unroll
            for (int mi = 0; mi < 2; ++mi)
#pragma unroll
                for (int ni = 0; ni < 4; ++ni)
                    acc[mi][ni] = __builtin_amdgcn_mfma_f32_16x16x32_bf16(
                        af[mi], bq[ni], acc[mi][ni], 0, 0, 0);
        }
        __syncthreads();
    }

    const int rq = (lane >> 4) << 2;
    float gv[4], bv2[4], biasv[4];
#pragma unroll
    for (int ni = 0; ni < 4; ++ni) {
        int col = wn0 + ni * 16 + lm;
        biasv[ni] = bias[col];
        gv[ni]    = g[col];
        bv2[ni]   = bb[col];
    }

    float sl[2][4] = {}, ssl[2][4] = {};
#pragma unroll
    for (int mi = 0; mi < 2; ++mi) {
#pragma unroll
        for (int r = 0; r < 4; ++r) {
            int row = m0 + mi * 16 + rq + r;
#pragma unroll
            for (int ni = 0; ni < 4; ++ni) {
                int col = wn0 + ni * 16 + lm;
                float resv = bflo((unsigned)xres[(size_t)row * DIM + col]);
                float v = acc[mi][ni][r] + biasv[ni] + resv;
                acc[mi][ni][r] = v;
                sl[mi][r]  += v;
                ssl[mi][r] += v * v;
            }
        }
    }
#pragma unroll
    for (int mi = 0; mi < 2; ++mi)
#pragma unroll
        for (int r = 0; r < 4; ++r) {
#pragma unroll
            for (int m = 1; m <= 8; m <<= 1) {
                sl[mi][r]  += __shfl_xor(sl[mi][r],  m, 64);
                ssl[mi][r] += __shfl_xor(ssl[mi][r], m, 64);
            }
        }
    if (lm == 0) {
#pragma unroll
        for (int mi = 0; mi < 2; ++mi)
#pragma unroll
            for (int r = 0; r < 4; ++r) {
                partS[wave][mi * 16 + rq + r]  = sl[mi][r];
                partSS[wave][mi * 16 + rq + r] = ssl[mi][r];
            }
    }
    __syncthreads();
    if (tid < 32) {
        float S = partS[0][tid] + partS[1][tid] + partS[2][tid] + partS[3][tid];
        float SS = partSS[0][tid] + partSS[1][tid] + partSS[2][tid] + partSS[3][tid];
        float mu  = S * (1.0f / DIM);
        float var = SS * (1.0f / DIM) - mu * mu;
        totMu[tid] = mu;
        totR[tid]  = rsqrtf(var + 1e-5f);
    }
    __syncthreads();

#pragma unroll
    for (int mi = 0; mi < 2; ++mi) {
#pragma unroll
        for (int r = 0; r < 4; ++r) {
            int lrow = mi * 16 + rq + r;
            int row  = m0 + lrow;
            float mu = totMu[lrow];
            float rv = totR[lrow];
#pragma unroll
            for (int ni = 0; ni < 4; ++ni) {
                int col = wn0 + ni * 16 + lm;
                float o = (acc[mi][ni][r] - mu) * rv * gv[ni] + bv2[ni];
                if (final_out) {
                    if (flag[0]) ((float*)dout)[(size_t)row * DIM + col] = o;
                    else ((unsigned short*)dout)[(size_t)row * DIM + col] = f2bf(o);
                } else {
                    xout[(size_t)row * DIM + col] = f2bf(o);
                }
            }
        }
    }
}

// ====== attention: block per node, wave per head; barrier-free (r5-proven) ===
__global__ __launch_bounds__(256) void attn_kernel(
    const unsigned short* __restrict__ q,    // [N, 256]
    const unsigned short* __restrict__ kv,   // [N, 512] (k | v)
    const int* __restrict__ nbr,             // [N, KCAP]
    const int* __restrict__ cnt,             // [N]
    unsigned short* __restrict__ ao)         // [N, 256]
{
    const int n    = blockIdx.x;
    const int tid  = threadIdx.x;
    const int h    = tid >> 6;
    const int lane = tid & 63;

    __shared__ float sc[NHEAD][KCAP];
    __shared__ int   nbs[NHEAD][KCAP];

    int deg = cnt[n];
    if (deg > KCAP) deg = KCAP;
    const bool iso = (deg == 0);
    if (iso) deg = 1;

    // per-wave neighbor list (no cross-wave sharing -> no barriers anywhere)
    if (lane < KCAP)
        nbs[h][lane] = (lane < deg) ? (iso ? n : nbr[n * KCAP + lane]) : 0;

    // ---- score-phase geometry: 8 lane-groups of 8 ----
    const int sub = lane & 7;
    const int grp = lane >> 3;
    const uint4 qu = *(const uint4*)&q[(size_t)n * DIM + h * DHEAD + sub * 8];
    const unsigned short* kbase = kv + h * DHEAD + sub * 8;
    const int nit = (deg + 7) >> 3;          // 1..6

    // ---- PV geometry: 4 lane-quarters of 16 ----
    const int quarter = lane >> 4;
    const int d0      = (lane & 15) * 4;
    const unsigned short* vbase = kv + 256 + h * DHEAD + d0;
    const int dmax = (deg + 3) & ~3;
    const int npv  = dmax >> 2;              // 1..12

    // ---- prefetch: issue ALL k loads, then all v loads (deg<=32 fast path) --
    uint4 ku[6];
#pragma unroll
    for (int it = 0; it < 6; ++it) {
        if (it < nit) {
            int nb = nbs[h][it * 8 + grp];
            ku[it] = *(const uint4*)&kbase[(size_t)nb * 512];
        }
    }
    uint2 vu[8];
#pragma unroll
    for (int it = 0; it < 8; ++it) {
        if (it < npv) {
            int nb = nbs[h][it * 4 + quarter];
            vu[it] = *(const uint2*)&vbase[(size_t)nb * 512];
        }
    }

    // ---- scores (consume ku; v loads stay in flight) ----
#pragma unroll
    for (int it = 0; it < 6; ++it) {
        if (it < nit) {
            int j = it * 8 + grp;
            uint4 kz = ku[it];
#if __has_builtin(__builtin_amdgcn_fdot2_f32_bf16)
            U32 a0{qu.x}, a1{qu.y}, a2{qu.z}, a3{qu.w};
            U32 b0{kz.x}, b1{kz.y}, b2{kz.z}, b3{kz.w};
            float p = __builtin_amdgcn_fdot2_f32_bf16(a0.v, b0.v, 0.0f, false);
            p = __builtin_amdgcn_fdot2_f32_bf16(a1.v, b1.v, p, false);
            p = __builtin_amdgcn_fdot2_f32_bf16(a2.v, b2.v, p, false);
            p = __builtin_amdgcn_fdot2_f32_bf16(a3.v, b3.v, p, false);
#else
            float p = bflo(qu.x) * bflo(kz.x);
            p = fmaf(bfhi(qu.x), bfhi(kz.x), p);
            p = fmaf(bflo(qu.y), bflo(kz.y), p);
            p = fmaf(bfhi(qu.y), bfhi(kz.y), p);
            p = fmaf(bflo(qu.z), bflo(kz.z), p);
            p = fmaf(bfhi(qu.z), bfhi(kz.z), p);
            p = fmaf(bflo(qu.w), bflo(kz.w), p);
            p = fmaf(bfhi(qu.w), bfhi(kz.w), p);
#endif
            p += __shfl_xor(p, 1, 64);
            p += __shfl_xor(p, 2, 64);
            p += __shfl_xor(p, 4, 64);
            if (sub == 0 && j < deg) sc[h][j] = p * 0.125f;   // 1/sqrt(64)
        }
    }

    // ---- softmax (per wave; sc is wave-private; v-gather hides under it) ----
    {
        float s  = (lane < deg) ? sc[h][lane] : -1e30f;
        float mx = s;
#pragma unroll
        for (int m = 32; m >= 1; m >>= 1) mx = fmaxf(mx, __shfl_xor(mx, m, 64));
        float e   = (lane < deg) ? __expf(s - mx) : 0.0f;
        float sum = e;
#pragma unroll
        for (int m = 32; m >= 1; m >>= 1) sum += __shfl_xor(sum, m, 64);
        float inv = 1.0f / sum;
        if (lane < KCAP) sc[h][lane] = e * inv;   // zero for lane >= deg
    }

    // ---- PV: consume prefetched v; dynamic remainder for deg > 32 ----
    {
        float a0 = 0.f, a1 = 0.f, a2 = 0.f, a3 = 0.f;
#pragma unroll
        for (int it = 0; it < 8; ++it) {
            if (it < npv) {
                float w = sc[h][it * 4 + quarter];
                uint2 u = vu[it];
                a0 = fmaf(w, bflo(u.x), a0);
                a1 = fmaf(w, bfhi(u.x), a1);
                a2 = fmaf(w, bflo(u.y), a2);
                a3 = fmaf(w, bfhi(u.y), a3);
            }
        }
        for (int j = 32; j < dmax; j += 4) {      // rare: deg in (32, 48]
            int j0 = j + quarter;
            int nb = nbs[h][j0];
            uint2 u = *(const uint2*)&vbase[(size_t)nb * 512];
            float w = sc[h][j0];
            a0 = fmaf(w, bflo(u.x), a0);
            a1 = fmaf(w, bfhi(u.x), a1);
            a2 = fmaf(w, bflo(u.y), a2);
            a3 = fmaf(w, bfhi(u.y), a3);
        }
        a0 += __shfl_xor(a0, 16, 64); a0 += __shfl_xor(a0, 32, 64);
        a1 += __shfl_xor(a1, 16, 64); a1 += __shfl_xor(a1, 32, 64);
        a2 += __shfl_xor(a2, 16, 64); a2 += __shfl_xor(a2, 32, 64);
        a3 += __shfl_xor(a3, 16, 64); a3 += __shfl_xor(a3, 32, 64);
        if (lane < 16) {
            uint2 o;
            o.x = (unsigned)f2bf(a0) | ((unsigned)f2bf(a1) << 16);
            o.y = (unsigned)f2bf(a2) | ((unsigned)f2bf(a3) << 16);
            *(uint2*)&ao[(size_t)n * DIM + h * DHEAD + d0] = o;
        }
    }
}

// =============== launch ======================================================
extern "C" void kernel_launch(void* const* d_in, const int* in_sizes, int n_in,
                              void* d_out, int out_size, void* d_ws, size_t ws_size,
                              hipStream_t stream) {
    const int* ei = (const int*)d_in[14];

    char* ws = (char*)d_ws;
    size_t off = 0;
    auto alloc = [&](size_t bytes) -> void* {
        void* p = ws + off;
        off = (off + bytes + 255) & ~(size_t)255;
        return p;
    };

    const int bidx[6] = { 0, 1, 2, 4, 6, 8 };
    const int bnn[6]  = { N_NODES * DIM, N_NODES * DIM,
                          NLAYER * 3 * DIM * DIM, NLAYER * DIM * DIM,
                          NLAYER * 2 * DIM * DIM, NLAYER * DIM * 2 * DIM };
    ConvBfArgs cb;
    unsigned short* canb[6];
    for (int i = 0; i < 6; ++i) {
        canb[i] = (unsigned short*)alloc((size_t)bnn[i] * 2);
        cb.src[i] = d_in[bidx[i]];
        cb.dst[i] = canb[i];
        cb.n[i]   = bnn[i];
    }
    const unsigned short* expr_b = canb[0];
    const unsigned short* spat_b = canb[1];
    const unsigned short* ipw    = canb[2];
    const unsigned short* opw    = canb[3];
    const unsigned short* w1     = canb[4];
    const unsigned short* w2     = canb[5];

    const int fidx[8] = { 3, 5, 7, 9, 10, 11, 12, 13 };
    const int fn[8]   = { NLAYER * 3 * DIM, NLAYER * DIM, NLAYER * 2 * DIM,
                          NLAYER * DIM, NLAYER * DIM, NLAYER * DIM,
                          NLAYER * DIM, NLAYER * DIM };
    ConvF32Args cf;
    float* canf[8];
    for (int i = 0; i < 8; ++i) {
        canf[i] = (float*)alloc((size_t)fn[i] * 4);
        cf.src[i] = d_in[fidx[i]];
        cf.dst[i] = canf[i];
        cf.n[i]   = fn[i];
    }

    unsigned short* x_buf  = (unsigned short*)alloc((size_t)N_NODES * DIM * 2);
    unsigned short* q_buf  = (unsigned short*)alloc((size_t)N_NODES * DIM * 2);
    unsigned short* kv_buf = (unsigned short*)alloc((size_t)N_NODES * 2 * DIM * 2);
    unsigned short* ao_buf = (unsigned short*)alloc((size_t)N_NODES * DIM * 2);
    unsigned short* h_buf  = (unsigned short*)alloc((size_t)N_NODES * 2 * DIM * 2);
    int* cnt  = (int*)alloc((size_t)N_NODES * 4);
    int* nbr  = (int*)alloc((size_t)N_NODES * KCAP * 4);
    int* flag = (int*)alloc(256);

    sniffzero_kernel<<<1 + (N_NODES + 255) / 256, 256, 0, stream>>>(
        (const unsigned short*)d_in[0], flag, cnt);
    // merged: bf16 conv | f32 conv | nbr build in ONE dispatch
    prep_kernel<<<dim3((N_NODES * DIM) / 1024, 8), 256, 0, stream>>>(
        cb, cf, ei, cnt, nbr, flag);

    for (int i = 0; i < NLAYER; ++i) {
        const unsigned short* Wqkv = ipw + (size_t)i * 3 * DIM * DIM;
        const float*          bqkv = canf[0] + (size_t)i * 3 * DIM;
        const unsigned short* xin  = (i == 0) ? expr_b : x_buf;

        // q | kv fused projection (64x128 tiles, high TLP)
        qkv_kernel<<<dim3(NBM64, 6), 256, 0, stream>>>(
            xin, spat_b, Wqkv, bqkv, q_buf, kv_buf, N_NODES);
        // attention (r5-proven guarded prefetch)
        attn_kernel<<<N_NODES, 256, 0, stream>>>(q_buf, kv_buf, nbr, cnt, ao_buf);
        // x = LN(xin + ao @ Wo^T + bo)  (BM=32, BK=64, grid 625, no tail)
        gemm_ln_kernel<<<NBM32, 256, 0, stream>>>(
            ao_buf, opw + (size_t)i * DIM * DIM, canf[1] + (size_t)i * DIM,
            xin, canf[4] + (size_t)i * DIM, canf[5] + (size_t)i * DIM,
            x_buf, nullptr, N_NODES, DIM, 0, flag);
        // h = gelu(x @ W1^T + b1)  (64x128 tiles)
        gemm_kernel<<<dim3(NBM64, 4), 256, 0, stream>>>(
            x_buf, w1 + (size_t)i * 2 * DIM * DIM, canf[2] + (size_t)i * 2 * DIM,
            h_buf, N_NODES, 2 * DIM, DIM, 1);
        // x = LN(x + h @ W2^T + b2); final layer -> d_out (dtype per flag)
        gemm_ln_kernel<<<NBM32, 256, 0, stream>>>(
            h_buf, w2 + (size_t)i * DIM * 2 * DIM, canf[3] + (size_t)i * DIM,
            x_buf, canf[6] + (size_t)i * DIM, canf[7] + (size_t)i * DIM,
            x_buf, d_out, N_NODES, 2 * DIM, (i == NLAYER - 1) ? 1 : 0, flag);
    }
}